// Round 6
// baseline (590.544 us; speedup 1.0000x reference)
//
#include <hip/hip_runtime.h>

// GCN: 3x (GEMM -> normalized edge aggregation -> +self +bias +ReLU),
// then global mean pool over 64 graphs, then FC [128 -> 10].
// Strategy: build CSR-by-dst once per call (no scan: row starts via a global
// atomic cursor), then PULL aggregation (one wave per node, no atomics;
// edge (src,norm) packed int2, shfl-broadcast, gathers pipelined 8-deep).
// Workspace ~57 MB: pull only reads HW, so its output reuses the buffer the
// preceding GEMM consumed (ping <-> HW).

#define N_NODES 50000
#define N_EDGES 600000
#define DIM 128      // IN == H == 128
#define OUT_DIM 10
#define N_GRAPHS 64
#define STRIP 128    // pool rows per block (128 -> 391 blocks, enough TLP)
#define GR 64        // gemm rows per block

__global__ void zero_kernel(int* __restrict__ p, int n) {
    int i = blockIdx.x * blockDim.x + threadIdx.x;
    for (; i < n; i += gridDim.x * blockDim.x) p[i] = 0;
}

// in-degree histogram over dst
__global__ void hist_kernel(const int* __restrict__ dst, int* __restrict__ deg) {
    int e = blockIdx.x * blockDim.x + threadIdx.x;
    if (e < N_EDGES) atomicAdd(&deg[dst[e]], 1);
}

// allocate CSR row starts via global cursor (row order in memory is arbitrary,
// each node just needs a contiguous slice); also deg-derived normalizers.
__global__ void node_prep_kernel(const int* __restrict__ deg, int* __restrict__ start,
                                 float* __restrict__ dinv, float* __restrict__ invdeg,
                                 int* __restrict__ gcur) {
    int i = blockIdx.x * blockDim.x + threadIdx.x;
    if (i < N_NODES) {
        int d = deg[i];
        start[i] = atomicAdd(gcur, d);
        float df = (float)d + 1.0f;      // +1 self-loop
        dinv[i]   = rsqrtf(df);
        invdeg[i] = 1.0f / df;
    }
}

// packed edge record: .x = src node, .y = float bits of norm
__global__ void csr_build_kernel(const int* __restrict__ src, const int* __restrict__ dst,
                                 const int* __restrict__ start, int* __restrict__ cursor,
                                 const float* __restrict__ dinv,
                                 int2* __restrict__ csr_pair) {
    int e = blockIdx.x * blockDim.x + threadIdx.x;
    if (e < N_EDGES) {
        int s = src[e], d = dst[e];
        int slot = start[d] + atomicAdd(&cursor[d], 1);
        int2 rec;
        rec.x = s;
        rec.y = __float_as_int(dinv[s] * dinv[d]);
        csr_pair[slot] = rec;
    }
}

// C[i][j] = sum_k A[i][k] * W[k][j].  Register-tiled: block = 64 rows x 128
// cols, 256 threads, each thread 8 rows x 4 cols (32 acc VGPRs). Per k-chunk
// of 4: 8 ds_read_b128 (A) + 4 float4 global (W) per thread -> 128 FMAs.
__global__ __launch_bounds__(256) void gemm_kernel(const float* __restrict__ A,
                                                   const float* __restrict__ W,
                                                   float* __restrict__ C) {
    __shared__ float4 Alds[GR][DIM / 4];
    int row0 = blockIdx.x * GR;
    int tid  = threadIdx.x;
    for (int i = tid; i < GR * (DIM / 4); i += 256) {
        int r = i >> 5, c = i & 31;
        int gr = row0 + r;
        Alds[r][c] = (gr < N_NODES) ? ((const float4*)A)[(size_t)gr * 32 + c]
                                    : make_float4(0.f, 0.f, 0.f, 0.f);
    }
    __syncthreads();
    int tx = tid & 31;   // cols tx*4 .. tx*4+3
    int ty = tid >> 5;   // rows ty*8 .. ty*8+7
    float acc[8][4];
#pragma unroll
    for (int r = 0; r < 8; ++r)
#pragma unroll
        for (int c = 0; c < 4; ++c) acc[r][c] = 0.f;
    const float4* W4 = (const float4*)W;
    for (int k = 0; k < DIM; k += 4) {
        float4 a[8];
#pragma unroll
        for (int r = 0; r < 8; ++r) a[r] = Alds[ty * 8 + r][k >> 2];
        float4 w0 = W4[(k + 0) * 32 + tx];
        float4 w1 = W4[(k + 1) * 32 + tx];
        float4 w2 = W4[(k + 2) * 32 + tx];
        float4 w3 = W4[(k + 3) * 32 + tx];
#pragma unroll
        for (int r = 0; r < 8; ++r) {
            acc[r][0] += a[r].x * w0.x + a[r].y * w1.x + a[r].z * w2.x + a[r].w * w3.x;
            acc[r][1] += a[r].x * w0.y + a[r].y * w1.y + a[r].z * w2.y + a[r].w * w3.y;
            acc[r][2] += a[r].x * w0.z + a[r].y * w1.z + a[r].z * w2.z + a[r].w * w3.z;
            acc[r][3] += a[r].x * w0.w + a[r].y * w1.w + a[r].z * w2.w + a[r].w * w3.w;
        }
    }
#pragma unroll
    for (int r = 0; r < 8; ++r) {
        int gr = row0 + ty * 8 + r;
        if (gr < N_NODES) {
            float4 o = make_float4(acc[r][0], acc[r][1], acc[r][2], acc[r][3]);
            ((float4*)C)[(size_t)gr * 32 + tx] = o;
        }
    }
}

// One wave per node; lane handles features (2*lane, 2*lane+1) as float2.
// Edge (src, norm) pre-loaded one-per-lane per 64-edge chunk (one dwordx2),
// broadcast via __shfl -> gather addresses ready without a dependent load;
// 8 gathers in flight per iteration. No atomics. Reads only HW, so Fout may
// alias the buffer the preceding GEMM read.
__global__ __launch_bounds__(256) void pull_kernel(const float* __restrict__ HW,
                                                   const int2* __restrict__ csr_pair,
                                                   const int* __restrict__ start,
                                                   const int* __restrict__ deg,
                                                   const float* __restrict__ invdeg,
                                                   const float* __restrict__ bias,
                                                   float* __restrict__ Fout) {
    int node = blockIdx.x * 4 + (threadIdx.x >> 6);
    int lane = threadIdx.x & 63;
    if (node >= N_NODES) return;
    const float2* HW2 = (const float2*)HW;
    int st = start[node];
    int dg = deg[node];
    float ax = 0.f, ay = 0.f;
    for (int base = 0; base < dg; base += 64) {
        int m = min(dg - base, 64);
        int2 rec = (lane < m) ? csr_pair[st + base + lane] : make_int2(0, 0);
        int   si = rec.x;
        float wi = __int_as_float(rec.y);
        int idx = 0;
        for (; idx + 8 <= m; idx += 8) {
            int s0 = __shfl(si, idx);     int s1 = __shfl(si, idx + 1);
            int s2 = __shfl(si, idx + 2); int s3 = __shfl(si, idx + 3);
            int s4 = __shfl(si, idx + 4); int s5 = __shfl(si, idx + 5);
            int s6 = __shfl(si, idx + 6); int s7 = __shfl(si, idx + 7);
            float w0 = __shfl(wi, idx);     float w1 = __shfl(wi, idx + 1);
            float w2 = __shfl(wi, idx + 2); float w3 = __shfl(wi, idx + 3);
            float w4 = __shfl(wi, idx + 4); float w5 = __shfl(wi, idx + 5);
            float w6 = __shfl(wi, idx + 6); float w7 = __shfl(wi, idx + 7);
            float2 v0 = HW2[(size_t)s0 * 64 + lane];
            float2 v1 = HW2[(size_t)s1 * 64 + lane];
            float2 v2 = HW2[(size_t)s2 * 64 + lane];
            float2 v3 = HW2[(size_t)s3 * 64 + lane];
            float2 v4 = HW2[(size_t)s4 * 64 + lane];
            float2 v5 = HW2[(size_t)s5 * 64 + lane];
            float2 v6 = HW2[(size_t)s6 * 64 + lane];
            float2 v7 = HW2[(size_t)s7 * 64 + lane];
            ax += v0.x * w0; ay += v0.y * w0;
            ax += v1.x * w1; ay += v1.y * w1;
            ax += v2.x * w2; ay += v2.y * w2;
            ax += v3.x * w3; ay += v3.y * w3;
            ax += v4.x * w4; ay += v4.y * w4;
            ax += v5.x * w5; ay += v5.y * w5;
            ax += v6.x * w6; ay += v6.y * w6;
            ax += v7.x * w7; ay += v7.y * w7;
        }
        for (; idx < m; ++idx) {
            int s = __shfl(si, idx);
            float w = __shfl(wi, idx);
            float2 v = HW2[(size_t)s * 64 + lane];
            ax += v.x * w; ay += v.y * w;
        }
    }
    float iv = invdeg[node];
    float2 hs = HW2[(size_t)node * 64 + lane];
    ax += hs.x * iv; ay += hs.y * iv;   // self-loop term h * (1/deg)
    float2 bb = ((const float2*)bias)[lane];
    ax = fmaxf(ax + bb.x, 0.f);
    ay = fmaxf(ay + bb.y, 0.f);
    float2 o; o.x = ax; o.y = ay;
    ((float2*)Fout)[(size_t)node * 64 + lane] = o;
}

__global__ void count_kernel(const int* __restrict__ batch, int* __restrict__ cnt) {
    int i = blockIdx.x * blockDim.x + threadIdx.x;
    if (i < N_NODES) atomicAdd(&cnt[batch[i]], 1);
}

// batch is sorted: run-length accumulate per thread-feature, flush on graph change.
__global__ __launch_bounds__(128) void pool_kernel(const float* __restrict__ F,
                                                   const int* __restrict__ batch,
                                                   float* __restrict__ pooled) {
    int s0 = blockIdx.x * STRIP;
    int f  = threadIdx.x;
    if (s0 >= N_NODES) return;
    int end = min(s0 + STRIP, N_NODES);
    int cur = batch[s0];
    float acc = 0.f;
    for (int n = s0; n < end; ++n) {
        int bn = batch[n];              // block-uniform
        if (bn != cur) {
            atomicAdd(&pooled[cur * DIM + f], acc);
            acc = 0.f; cur = bn;
        }
        acc += F[(size_t)n * DIM + f];  // coalesced 512B per n
    }
    atomicAdd(&pooled[cur * DIM + f], acc);
}

__global__ __launch_bounds__(640) void fc_kernel(const float* __restrict__ pooled,
                                                 const int* __restrict__ cnt,
                                                 const float* __restrict__ Wfc,
                                                 const float* __restrict__ bfc,
                                                 float* __restrict__ out) {
    int t = threadIdx.x;
    if (t >= N_GRAPHS * OUT_DIM) return;
    int g = t / OUT_DIM, o = t % OUT_DIM;
    float inv = 1.0f / fmaxf((float)cnt[g], 1.0f);
    float acc = bfc[o];
#pragma unroll 8
    for (int k = 0; k < DIM; ++k)
        acc += pooled[g * DIM + k] * inv * Wfc[k * OUT_DIM + o];
    out[g * OUT_DIM + o] = acc;
}

extern "C" void kernel_launch(void* const* d_in, const int* in_sizes, int n_in,
                              void* d_out, int out_size, void* d_ws, size_t ws_size,
                              hipStream_t stream) {
    const float* x    = (const float*)d_in[0];
    const int*   ei   = (const int*)d_in[1];     // [2, E]
    const int*   batch= (const int*)d_in[2];
    const float* W1   = (const float*)d_in[3];
    const float* b1   = (const float*)d_in[4];
    const float* W2   = (const float*)d_in[5];
    const float* b2   = (const float*)d_in[6];
    const float* W3   = (const float*)d_in[7];
    const float* b3   = (const float*)d_in[8];
    const float* Wfc  = (const float*)d_in[9];
    const float* bfc  = (const float*)d_in[10];
    float* out = (float*)d_out;

    const int* src = ei;
    const int* dst = ei + N_EDGES;

    // workspace layout (4-byte elements), ~57 MB total
    char* ws = (char*)d_ws;
    size_t o = 0;
    float* HW   = (float*)(ws + o); o += (size_t)N_NODES * DIM * 4;   // GEMM out
    float* PB   = (float*)(ws + o); o += (size_t)N_NODES * DIM * 4;   // pull out / GEMM in
    // ---- zeroed region start ----
    int*   deg    = (int*)(ws + o); o += (size_t)N_NODES * 4;
    int*   cursor = (int*)(ws + o); o += (size_t)N_NODES * 4;
    float* pooled = (float*)(ws + o); o += (size_t)N_GRAPHS * DIM * 4;
    int*   cnt    = (int*)(ws + o); o += (size_t)N_GRAPHS * 4;
    int*   gcur   = (int*)(ws + o); o += 4;
    o = (o + 7) & ~(size_t)7;  // align for int2
    // ---- zeroed region end ----
    int*   startv = (int*)(ws + o); o += (size_t)N_NODES * 4;
    float* dinv   = (float*)(ws + o); o += (size_t)N_NODES * 4;
    float* invdeg = (float*)(ws + o); o += (size_t)N_NODES * 4;
    int2*  csr_pair = (int2*)(ws + o); o += (size_t)N_EDGES * 8;

    const int nzero = 2 * N_NODES + N_GRAPHS * DIM + N_GRAPHS + 1;

    zero_kernel<<<(nzero + 255) / 256, 256, 0, stream>>>(deg, nzero);
    hist_kernel<<<(N_EDGES + 255) / 256, 256, 0, stream>>>(dst, deg);
    node_prep_kernel<<<(N_NODES + 255) / 256, 256, 0, stream>>>(deg, startv, dinv, invdeg, gcur);
    csr_build_kernel<<<(N_EDGES + 255) / 256, 256, 0, stream>>>(src, dst, startv, cursor,
                                                                dinv, csr_pair);

    const int ggrid = (N_NODES + GR - 1) / GR;
    const int pgrid = (N_NODES + 3) / 4;

    // layer 1: x -> HW -> PB
    gemm_kernel<<<ggrid, 256, 0, stream>>>(x, W1, HW);
    pull_kernel<<<pgrid, 256, 0, stream>>>(HW, csr_pair, startv, deg, invdeg, b1, PB);
    // layer 2: PB -> HW -> PB  (pull reads only HW, safe to overwrite PB)
    gemm_kernel<<<ggrid, 256, 0, stream>>>(PB, W2, HW);
    pull_kernel<<<pgrid, 256, 0, stream>>>(HW, csr_pair, startv, deg, invdeg, b2, PB);
    // layer 3: PB -> HW -> PB
    gemm_kernel<<<ggrid, 256, 0, stream>>>(PB, W3, HW);
    pull_kernel<<<pgrid, 256, 0, stream>>>(HW, csr_pair, startv, deg, invdeg, b3, PB);

    count_kernel<<<(N_NODES + 255) / 256, 256, 0, stream>>>(batch, cnt);
    pool_kernel<<<(N_NODES + STRIP - 1) / STRIP, 128, 0, stream>>>(PB, batch, pooled);
    fc_kernel<<<1, 640, 0, stream>>>(pooled, cnt, Wfc, bfc, out);
}

// Round 7
// 441.744 us; speedup vs baseline: 1.3368x; 1.3368x over previous
//
#include <hip/hip_runtime.h>

// GCN: 3x (GEMM -> normalized edge aggregation -> +self +bias +ReLU),
// then global mean pool over 64 graphs, then FC [128 -> 10].
// Strategy: build CSR-by-dst once per call (no scan: row starts via a global
// atomic cursor), then PULL aggregation (one wave per node, no atomics;
// edge (src,norm) packed int2, shfl-broadcast, gathers pipelined 8-deep).
// Graph counts via sorted-batch boundary detection (R6: count_kernel's
// same-address atomics were 153us = 26% of runtime; bounds_kernel is ~5us).

#define N_NODES 50000
#define N_EDGES 600000
#define DIM 128      // IN == H == 128
#define OUT_DIM 10
#define N_GRAPHS 64
#define STRIP 128    // pool rows per block (128 -> 391 blocks, enough TLP)
#define GR 64        // gemm rows per block

__global__ void zero_kernel(int* __restrict__ p, int n) {
    int i = blockIdx.x * blockDim.x + threadIdx.x;
    for (; i < n; i += gridDim.x * blockDim.x) p[i] = 0;
}

// in-degree histogram over dst
__global__ void hist_kernel(const int* __restrict__ dst, int* __restrict__ deg) {
    int e = blockIdx.x * blockDim.x + threadIdx.x;
    if (e < N_EDGES) atomicAdd(&deg[dst[e]], 1);
}

// allocate CSR row starts via global cursor (row order in memory is arbitrary,
// each node just needs a contiguous slice); also deg-derived normalizers.
__global__ void node_prep_kernel(const int* __restrict__ deg, int* __restrict__ start,
                                 float* __restrict__ dinv, float* __restrict__ invdeg,
                                 int* __restrict__ gcur) {
    int i = blockIdx.x * blockDim.x + threadIdx.x;
    if (i < N_NODES) {
        int d = deg[i];
        start[i] = atomicAdd(gcur, d);
        float df = (float)d + 1.0f;      // +1 self-loop
        dinv[i]   = rsqrtf(df);
        invdeg[i] = 1.0f / df;
    }
}

// packed edge record: .x = src node, .y = float bits of norm
__global__ void csr_build_kernel(const int* __restrict__ src, const int* __restrict__ dst,
                                 const int* __restrict__ start, int* __restrict__ cursor,
                                 const float* __restrict__ dinv,
                                 int2* __restrict__ csr_pair) {
    int e = blockIdx.x * blockDim.x + threadIdx.x;
    if (e < N_EDGES) {
        int s = src[e], d = dst[e];
        int slot = start[d] + atomicAdd(&cursor[d], 1);
        int2 rec;
        rec.x = s;
        rec.y = __float_as_int(dinv[s] * dinv[d]);
        csr_pair[slot] = rec;
    }
}

// C[i][j] = sum_k A[i][k] * W[k][j].  Register-tiled: block = 64 rows x 128
// cols, 256 threads, each thread 8 rows x 4 cols (32 acc VGPRs). Per k-chunk
// of 4: 8 ds_read_b128 (A) + 4 float4 global (W) per thread -> 128 FMAs.
__global__ __launch_bounds__(256) void gemm_kernel(const float* __restrict__ A,
                                                   const float* __restrict__ W,
                                                   float* __restrict__ C) {
    __shared__ float4 Alds[GR][DIM / 4];
    int row0 = blockIdx.x * GR;
    int tid  = threadIdx.x;
    for (int i = tid; i < GR * (DIM / 4); i += 256) {
        int r = i >> 5, c = i & 31;
        int gr = row0 + r;
        Alds[r][c] = (gr < N_NODES) ? ((const float4*)A)[(size_t)gr * 32 + c]
                                    : make_float4(0.f, 0.f, 0.f, 0.f);
    }
    __syncthreads();
    int tx = tid & 31;   // cols tx*4 .. tx*4+3
    int ty = tid >> 5;   // rows ty*8 .. ty*8+7
    float acc[8][4];
#pragma unroll
    for (int r = 0; r < 8; ++r)
#pragma unroll
        for (int c = 0; c < 4; ++c) acc[r][c] = 0.f;
    const float4* W4 = (const float4*)W;
    for (int k = 0; k < DIM; k += 4) {
        float4 a[8];
#pragma unroll
        for (int r = 0; r < 8; ++r) a[r] = Alds[ty * 8 + r][k >> 2];
        float4 w0 = W4[(k + 0) * 32 + tx];
        float4 w1 = W4[(k + 1) * 32 + tx];
        float4 w2 = W4[(k + 2) * 32 + tx];
        float4 w3 = W4[(k + 3) * 32 + tx];
#pragma unroll
        for (int r = 0; r < 8; ++r) {
            acc[r][0] += a[r].x * w0.x + a[r].y * w1.x + a[r].z * w2.x + a[r].w * w3.x;
            acc[r][1] += a[r].x * w0.y + a[r].y * w1.y + a[r].z * w2.y + a[r].w * w3.y;
            acc[r][2] += a[r].x * w0.z + a[r].y * w1.z + a[r].z * w2.z + a[r].w * w3.z;
            acc[r][3] += a[r].x * w0.w + a[r].y * w1.w + a[r].z * w2.w + a[r].w * w3.w;
        }
    }
#pragma unroll
    for (int r = 0; r < 8; ++r) {
        int gr = row0 + ty * 8 + r;
        if (gr < N_NODES) {
            float4 o = make_float4(acc[r][0], acc[r][1], acc[r][2], acc[r][3]);
            ((float4*)C)[(size_t)gr * 32 + tx] = o;
        }
    }
}

// One wave per node; lane handles features (2*lane, 2*lane+1) as float2.
// Edge (src, norm) pre-loaded one-per-lane per 64-edge chunk (one dwordx2),
// broadcast via __shfl -> gather addresses ready without a dependent load;
// 8 gathers in flight per iteration. No atomics. Reads only HW, so Fout may
// alias the buffer the preceding GEMM read.
__global__ __launch_bounds__(256) void pull_kernel(const float* __restrict__ HW,
                                                   const int2* __restrict__ csr_pair,
                                                   const int* __restrict__ start,
                                                   const int* __restrict__ deg,
                                                   const float* __restrict__ invdeg,
                                                   const float* __restrict__ bias,
                                                   float* __restrict__ Fout) {
    int node = blockIdx.x * 4 + (threadIdx.x >> 6);
    int lane = threadIdx.x & 63;
    if (node >= N_NODES) return;
    const float2* HW2 = (const float2*)HW;
    int st = start[node];
    int dg = deg[node];
    float ax = 0.f, ay = 0.f;
    for (int base = 0; base < dg; base += 64) {
        int m = min(dg - base, 64);
        int2 rec = (lane < m) ? csr_pair[st + base + lane] : make_int2(0, 0);
        int   si = rec.x;
        float wi = __int_as_float(rec.y);
        int idx = 0;
        for (; idx + 8 <= m; idx += 8) {
            int s0 = __shfl(si, idx);     int s1 = __shfl(si, idx + 1);
            int s2 = __shfl(si, idx + 2); int s3 = __shfl(si, idx + 3);
            int s4 = __shfl(si, idx + 4); int s5 = __shfl(si, idx + 5);
            int s6 = __shfl(si, idx + 6); int s7 = __shfl(si, idx + 7);
            float w0 = __shfl(wi, idx);     float w1 = __shfl(wi, idx + 1);
            float w2 = __shfl(wi, idx + 2); float w3 = __shfl(wi, idx + 3);
            float w4 = __shfl(wi, idx + 4); float w5 = __shfl(wi, idx + 5);
            float w6 = __shfl(wi, idx + 6); float w7 = __shfl(wi, idx + 7);
            float2 v0 = HW2[(size_t)s0 * 64 + lane];
            float2 v1 = HW2[(size_t)s1 * 64 + lane];
            float2 v2 = HW2[(size_t)s2 * 64 + lane];
            float2 v3 = HW2[(size_t)s3 * 64 + lane];
            float2 v4 = HW2[(size_t)s4 * 64 + lane];
            float2 v5 = HW2[(size_t)s5 * 64 + lane];
            float2 v6 = HW2[(size_t)s6 * 64 + lane];
            float2 v7 = HW2[(size_t)s7 * 64 + lane];
            ax += v0.x * w0; ay += v0.y * w0;
            ax += v1.x * w1; ay += v1.y * w1;
            ax += v2.x * w2; ay += v2.y * w2;
            ax += v3.x * w3; ay += v3.y * w3;
            ax += v4.x * w4; ay += v4.y * w4;
            ax += v5.x * w5; ay += v5.y * w5;
            ax += v6.x * w6; ay += v6.y * w6;
            ax += v7.x * w7; ay += v7.y * w7;
        }
        for (; idx < m; ++idx) {
            int s = __shfl(si, idx);
            float w = __shfl(wi, idx);
            float2 v = HW2[(size_t)s * 64 + lane];
            ax += v.x * w; ay += v.y * w;
        }
    }
    float iv = invdeg[node];
    float2 hs = HW2[(size_t)node * 64 + lane];
    ax += hs.x * iv; ay += hs.y * iv;   // self-loop term h * (1/deg)
    float2 bb = ((const float2*)bias)[lane];
    ax = fmaxf(ax + bb.x, 0.f);
    ay = fmaxf(ay + bb.y, 0.f);
    float2 o; o.x = ax; o.y = ay;
    ((float2*)Fout)[(size_t)node * 64 + lane] = o;
}

// batch is sorted: graph g occupies [startg[g], endg[g]). Boundary detection,
// no atomics (R6: atomic histogram on sorted batch serialized ~781-deep).
__global__ void bounds_kernel(const int* __restrict__ batch,
                              int* __restrict__ startg, int* __restrict__ endg) {
    int i = blockIdx.x * blockDim.x + threadIdx.x;
    if (i >= N_NODES) return;
    int b = batch[i];
    if (i == 0 || batch[i - 1] != b) startg[b] = i;
    if (i == N_NODES - 1 || batch[i + 1] != b) endg[b] = i + 1;
}

// batch is sorted: run-length accumulate per thread-feature, flush on graph change.
__global__ __launch_bounds__(128) void pool_kernel(const float* __restrict__ F,
                                                   const int* __restrict__ batch,
                                                   float* __restrict__ pooled) {
    int s0 = blockIdx.x * STRIP;
    int f  = threadIdx.x;
    if (s0 >= N_NODES) return;
    int end = min(s0 + STRIP, N_NODES);
    int cur = batch[s0];
    float acc = 0.f;
    for (int n = s0; n < end; ++n) {
        int bn = batch[n];              // block-uniform
        if (bn != cur) {
            atomicAdd(&pooled[cur * DIM + f], acc);
            acc = 0.f; cur = bn;
        }
        acc += F[(size_t)n * DIM + f];  // coalesced 512B per n
    }
    atomicAdd(&pooled[cur * DIM + f], acc);
}

__global__ __launch_bounds__(640) void fc_kernel(const float* __restrict__ pooled,
                                                 const int* __restrict__ startg,
                                                 const int* __restrict__ endg,
                                                 const float* __restrict__ Wfc,
                                                 const float* __restrict__ bfc,
                                                 float* __restrict__ out) {
    int t = threadIdx.x;
    if (t >= N_GRAPHS * OUT_DIM) return;
    int g = t / OUT_DIM, o = t % OUT_DIM;
    int c = endg[g] - startg[g];
    float inv = 1.0f / fmaxf((float)c, 1.0f);
    float acc = bfc[o];
#pragma unroll 8
    for (int k = 0; k < DIM; ++k)
        acc += pooled[g * DIM + k] * inv * Wfc[k * OUT_DIM + o];
    out[g * OUT_DIM + o] = acc;
}

extern "C" void kernel_launch(void* const* d_in, const int* in_sizes, int n_in,
                              void* d_out, int out_size, void* d_ws, size_t ws_size,
                              hipStream_t stream) {
    const float* x    = (const float*)d_in[0];
    const int*   ei   = (const int*)d_in[1];     // [2, E]
    const int*   batch= (const int*)d_in[2];
    const float* W1   = (const float*)d_in[3];
    const float* b1   = (const float*)d_in[4];
    const float* W2   = (const float*)d_in[5];
    const float* b2   = (const float*)d_in[6];
    const float* W3   = (const float*)d_in[7];
    const float* b3   = (const float*)d_in[8];
    const float* Wfc  = (const float*)d_in[9];
    const float* bfc  = (const float*)d_in[10];
    float* out = (float*)d_out;

    const int* src = ei;
    const int* dst = ei + N_EDGES;

    // workspace layout (4-byte elements), ~57 MB total
    char* ws = (char*)d_ws;
    size_t o = 0;
    float* HW   = (float*)(ws + o); o += (size_t)N_NODES * DIM * 4;   // GEMM out
    float* PB   = (float*)(ws + o); o += (size_t)N_NODES * DIM * 4;   // pull out / GEMM in
    // ---- zeroed region start ----
    int*   deg    = (int*)(ws + o); o += (size_t)N_NODES * 4;
    int*   cursor = (int*)(ws + o); o += (size_t)N_NODES * 4;
    float* pooled = (float*)(ws + o); o += (size_t)N_GRAPHS * DIM * 4;
    int*   startg = (int*)(ws + o); o += (size_t)N_GRAPHS * 4;
    int*   endg   = (int*)(ws + o); o += (size_t)N_GRAPHS * 4;
    int*   gcur   = (int*)(ws + o); o += 4;
    o = (o + 7) & ~(size_t)7;  // align for int2
    // ---- zeroed region end ----
    int*   startv = (int*)(ws + o); o += (size_t)N_NODES * 4;
    float* dinv   = (float*)(ws + o); o += (size_t)N_NODES * 4;
    float* invdeg = (float*)(ws + o); o += (size_t)N_NODES * 4;
    int2*  csr_pair = (int2*)(ws + o); o += (size_t)N_EDGES * 8;

    const int nzero = 2 * N_NODES + N_GRAPHS * DIM + 2 * N_GRAPHS + 1;

    zero_kernel<<<(nzero + 255) / 256, 256, 0, stream>>>(deg, nzero);
    hist_kernel<<<(N_EDGES + 255) / 256, 256, 0, stream>>>(dst, deg);
    node_prep_kernel<<<(N_NODES + 255) / 256, 256, 0, stream>>>(deg, startv, dinv, invdeg, gcur);
    csr_build_kernel<<<(N_EDGES + 255) / 256, 256, 0, stream>>>(src, dst, startv, cursor,
                                                                dinv, csr_pair);

    const int ggrid = (N_NODES + GR - 1) / GR;
    const int pgrid = (N_NODES + 3) / 4;

    // layer 1: x -> HW -> PB
    gemm_kernel<<<ggrid, 256, 0, stream>>>(x, W1, HW);
    pull_kernel<<<pgrid, 256, 0, stream>>>(HW, csr_pair, startv, deg, invdeg, b1, PB);
    // layer 2: PB -> HW -> PB  (pull reads only HW, safe to overwrite PB)
    gemm_kernel<<<ggrid, 256, 0, stream>>>(PB, W2, HW);
    pull_kernel<<<pgrid, 256, 0, stream>>>(HW, csr_pair, startv, deg, invdeg, b2, PB);
    // layer 3: PB -> HW -> PB
    gemm_kernel<<<ggrid, 256, 0, stream>>>(PB, W3, HW);
    pull_kernel<<<pgrid, 256, 0, stream>>>(HW, csr_pair, startv, deg, invdeg, b3, PB);

    bounds_kernel<<<(N_NODES + 255) / 256, 256, 0, stream>>>(batch, startg, endg);
    pool_kernel<<<(N_NODES + STRIP - 1) / STRIP, 128, 0, stream>>>(PB, batch, pooled);
    fc_kernel<<<1, 640, 0, stream>>>(pooled, startg, endg, Wfc, bfc, out);
}